// Round 1
// baseline (679.856 us; speedup 1.0000x reference)
//
#include <hip/hip_runtime.h>
#include <stdint.h>

typedef unsigned short u16;
typedef _Float16 f16;
typedef f16 f16x4 __attribute__((ext_vector_type(4)));
typedef f16 f16x8 __attribute__((ext_vector_type(8)));
typedef float f32x16 __attribute__((ext_vector_type(16)));

// Problem constants
#define M_     4
#define B_     256
#define NPG_   64
#define N_     (B_*NPG_)    // 16384
#define DEG_   8
#define E_     (N_*DEG_)    // 131072
#define DF_    16
#define D_     256
#define L_     5
#define NA_    2
#define TASKS_ 10

// R9: all-vector LDS restructure.
//  - Layer reassociated: u = h@W1 ; z = relu(A'u + b1), A' = Adj + (1+eps)I ; h' = relu(z@W2 + b2).
//  - Dual layout ping-pong in one LDS region: R (node-major, HROW) and T (feature-major, TROW).
//    W1: form A, R->T (b64 writes). Adj: A=uT rows, B=Adj rows, T->R (b128 reads, b64 writes).
//    W2: form B (A=W2^T global, B=z R-rows), R->R. Head: form A R->T, mean = b128 row sums.
//  - No scalar ds_read_u16 gathers / ds_write_u16 remain in any GEMM.
#define HROW 520            // u16 row stride of node-major split-h (1040 B, 16B aligned)
#define TROW 136            // u16 row stride of feature-major split-u (272 B, 16B aligned)
#define MFMA16(a,b,c) __builtin_amdgcn_mfma_f32_32x32x16_f16(a,b,c,0,0,0)

// ---------------- f16 helpers ----------------
__device__ __forceinline__ u16 h_bits(f16 h) { union { f16 h; u16 u; } c; c.h = h; return c.u; }
__device__ __forceinline__ f16 bits_h(u16 u) { union { u16 u; f16 h; } c; c.u = u; return c.h; }
__device__ __forceinline__ float h2f(u16 u) { return (float)bits_h(u); }
__device__ __forceinline__ void split_f16(float v, u16& hi, u16& lo) {
  f16 h = (f16)v;
  f16 l = (f16)(v - (float)h);
  hi = h_bits(h); lo = h_bits(l);
}

// R layout: u16 index of the 8-elem hi group for (node row, feature chunk); lo group at +8.
// (R6 swizzle — kept; bank-enumeration: conflict-free for b128 row reads and b64 run writes.)
__device__ __forceinline__ int haddr8(int row, int chunk) {
  return row * HROW + ((chunk ^ (row & 7)) << 4);
}
// T layout: u16 index of the 8-elem hi group for (feature row d, node chunk c); lo group at +8.
__device__ __forceinline__ int taddr8(int d, int c) {
  return d * TROW + ((c ^ (d & 7)) << 4);
}

// ---------------- Threefry-2x32 (exact JAX semantics) ----------------
__device__ __forceinline__ uint32_t rotl32(uint32_t v, int r) { return (v << r) | (v >> (32 - r)); }
__device__ __forceinline__ void threefry2x32(uint32_t k0, uint32_t k1, uint32_t x0, uint32_t x1,
                                             uint32_t& o0, uint32_t& o1) {
  const uint32_t ks2 = k0 ^ k1 ^ 0x1BD11BDAu;
  x0 += k0; x1 += k1;
#define TFR(r) { x0 += x1; x1 = rotl32(x1, r); x1 ^= x0; }
  TFR(13) TFR(15) TFR(26) TFR(6)   x0 += k1;  x1 += ks2 + 1u;
  TFR(17) TFR(29) TFR(16) TFR(24)  x0 += ks2; x1 += k0 + 2u;
  TFR(13) TFR(15) TFR(26) TFR(6)   x0 += k0;  x1 += k1 + 3u;
  TFR(17) TFR(29) TFR(16) TFR(24)  x0 += k1;  x1 += ks2 + 4u;
  TFR(13) TFR(15) TFR(26) TFR(6)   x0 += ks2; x1 += k0 + 5u;
#undef TFR
  o0 = x0; o1 = x1;
}

// ---------------- G1 (form A): out = in @ W (+bias, relu) ; reads R, writes T ----------------
// Wave w owns output cols 32w..32w+31 for both node blocks. W streamed from global (L2-resident).
template<int TERMS>
__device__ __forceinline__ void gemm_w_RT(u16* __restrict__ hfU, const u16* __restrict__ WTm,
                                          const float* __restrict__ bias, bool do_relu) {
  const int tid = threadIdx.x;
  const int lane = tid & 63, w = tid >> 6;
  const int l31 = lane & 31, lh = lane >> 5;
  const int col = w * 32 + l31;
  const float bv = bias ? bias[col] : 0.f;
  f32x16 acc0 = {}, acc1 = {};
  const u16* Bbase = WTm + col * 8;
#pragma unroll
  for (int ks = 0; ks < 16; ++ks) {
    const int chunk = ks * 2 + lh;
    const int a0 = haddr8(l31, chunk);
    const int a1 = haddr8(32 + l31, chunk);
    const f16x8 ahi0 = *(const f16x8*)(hfU + a0);
    const f16x8 ahi1 = *(const f16x8*)(hfU + a1);
    const f16x8 bh = *(const f16x8*)(Bbase + chunk * 2048);
    if (TERMS == 3) {
      const f16x8 alo0 = *(const f16x8*)(hfU + a0 + 8);
      const f16x8 alo1 = *(const f16x8*)(hfU + a1 + 8);
      const f16x8 bl = *(const f16x8*)(Bbase + chunk * 2048 + 65536);
      acc0 = MFMA16(ahi0, bh, acc0);
      acc0 = MFMA16(ahi0, bl, acc0);
      acc0 = MFMA16(alo0, bh, acc0);
      acc1 = MFMA16(ahi1, bh, acc1);
      acc1 = MFMA16(ahi1, bl, acc1);
      acc1 = MFMA16(alo1, bh, acc1);
    } else {
      acc0 = MFMA16(ahi0, bh, acc0);
      acc1 = MFMA16(ahi1, bh, acc1);
    }
  }
  __syncthreads();                       // S1: all R reads done, region dead
  // C frag: node row rr=(r&3)+8q+4lh, col fixed -> T rows are node-runs-of-4 -> b64 writes
#pragma unroll
  for (int q = 0; q < 4; ++q) {
    f16x4 h4a, l4a, h4b, l4b;
#pragma unroll
    for (int e = 0; e < 4; ++e) {
      float v0 = acc0[q * 4 + e] + bv;
      float v1 = acc1[q * 4 + e] + bv;
      if (do_relu) { v0 = fmaxf(v0, 0.f); v1 = fmaxf(v1, 0.f); }
      if (TERMS == 3) {
        u16 hi, lo;
        split_f16(v0, hi, lo); h4a[e] = bits_h(hi); l4a[e] = bits_h(lo);
        split_f16(v1, hi, lo); h4b[e] = bits_h(hi); l4b[e] = bits_h(lo);
      } else {
        h4a[e] = (f16)v0; h4b[e] = (f16)v1;
      }
    }
    const int t0 = taddr8(col, q) + 4 * lh;       // nodes 8q+4lh..+3
    const int t1 = taddr8(col, 4 + q) + 4 * lh;   // nodes 32+...
    *(f16x4*)(hfU + t0) = h4a;
    *(f16x4*)(hfU + t1) = h4b;
    if (TERMS == 3) { *(f16x4*)(hfU + t0 + 8) = l4a; *(f16x4*)(hfU + t1 + 8) = l4b; }
  }
  __syncthreads();                       // S2: T ready
}

// ---------------- G2: z = relu(A' @ u + b1), A' = Adj + (1+eps)I ; reads T, writes R ----------
// Computes z^T: A = u^T rows (b128 from T), B = A' rows (b128 from AdjU). Wave w owns d-block w.
template<int TERMS>
__device__ __forceinline__ void gemm_adj_TR(u16* __restrict__ hfU, const u16* __restrict__ AdjU,
                                            const float* __restrict__ bias, int slow,
                                            const float* __restrict__ diagC, float epsl) {
  const int tid = threadIdx.x;
  const int lane = tid & 63, w = tid >> 6;
  const int l31 = lane & 31, lh = lane >> 5;
  const int drow = w * 32 + l31;          // T row (feature) this lane feeds as A
  f32x16 acc0 = {}, acc1 = {};
#pragma unroll
  for (int kk = 0; kk < 4; ++kk) {
    const int chunk = kk * 2 + lh;
    const int ta = taddr8(drow, chunk);
    const f16x8 uh = *(const f16x8*)(hfU + ta);
    const f16x8 B0 = *(const f16x8*)(AdjU + l31 * 72 + chunk * 8);
    const f16x8 B1 = *(const f16x8*)(AdjU + (32 + l31) * 72 + chunk * 8);
    acc0 = MFMA16(uh, B0, acc0);
    acc1 = MFMA16(uh, B1, acc1);
    if (TERMS == 3) {
      const f16x8 ul = *(const f16x8*)(hfU + ta + 8);
      acc0 = MFMA16(ul, B0, acc0);
      acc1 = MFMA16(ul, B1, acc1);
    }
  }
  // exact-diag correction — only when (1+eps) is not f16-exact (never for eps=0 inputs)
  if (slow) {
    const int i0 = l31, i1 = 32 + l31;
    const float v0d = diagC[i0] + epsl, v1d = diagC[i1] + epsl;
    const float r0 = v0d - h2f(h_bits((f16)v0d));
    const float r1 = v1d - h2f(h_bits((f16)v1d));
#pragma unroll
    for (int r = 0; r < 16; ++r) {
      const int dp = w * 32 + (r & 3) + 8 * (r >> 2) + 4 * lh;
      const int a0 = taddr8(dp, i0 >> 3) + (i0 & 7);
      const int a1 = taddr8(dp, i1 >> 3) + (i1 & 7);
      float u0 = h2f(hfU[a0]);
      float u1 = h2f(hfU[a1]);
      if (TERMS == 3) { u0 += h2f(hfU[a0 + 8]); u1 += h2f(hfU[a1 + 8]); }
      acc0[r] += r0 * u0;
      acc1[r] += r1 * u1;
    }
  }
  __syncthreads();                       // S1: all T reads done
  // C frag: col = node i (l31 / 32+l31), rows = d-runs-of-4 -> R writes are b64
#pragma unroll
  for (int q = 0; q < 4; ++q) {
    f16x4 h4a, l4a, h4b, l4b;
#pragma unroll
    for (int e = 0; e < 4; ++e) {
      const int r = q * 4 + e;
      const float bq = bias[w * 32 + 8 * q + 4 * lh + e];
      float v0 = fmaxf(acc0[r] + bq, 0.f);
      float v1 = fmaxf(acc1[r] + bq, 0.f);
      if (TERMS == 3) {
        u16 hi, lo;
        split_f16(v0, hi, lo); h4a[e] = bits_h(hi); l4a[e] = bits_h(lo);
        split_f16(v1, hi, lo); h4b[e] = bits_h(hi); l4b[e] = bits_h(lo);
      } else {
        h4a[e] = (f16)v0; h4b[e] = (f16)v1;
      }
    }
    const int c = w * 4 + q;
    const int a0 = haddr8(l31, c) + 4 * lh;
    const int a1 = haddr8(32 + l31, c) + 4 * lh;
    *(f16x4*)(hfU + a0) = h4a;
    *(f16x4*)(hfU + a1) = h4b;
    if (TERMS == 3) { *(f16x4*)(hfU + a0 + 8) = l4a; *(f16x4*)(hfU + a1 + 8) = l4b; }
  }
  __syncthreads();                       // S2: R ready
}

// ---------------- G3 (form B): out = in @ W (+bias, relu) ; reads R, writes R ----------------
// Computes out^T = W^T @ in^T: A = W^T rows (global), B = in rows (b128 from R).
template<int TERMS>
__device__ __forceinline__ void gemm_w_RR(u16* __restrict__ hfU, const u16* __restrict__ WTm,
                                          const float* __restrict__ bias, bool do_relu) {
  const int tid = threadIdx.x;
  const int lane = tid & 63, w = tid >> 6;
  const int l31 = lane & 31, lh = lane >> 5;
  f32x16 acc0 = {}, acc1 = {};
  const u16* Abase = WTm + (w * 32 + l31) * 8;   // W^T row d' = w*32+l31
#pragma unroll
  for (int ks = 0; ks < 16; ++ks) {
    const int chunk = ks * 2 + lh;
    const f16x8 Wh = *(const f16x8*)(Abase + chunk * 2048);
    const int b0 = haddr8(l31, chunk);
    const int b1_ = haddr8(32 + l31, chunk);
    const f16x8 Xh0 = *(const f16x8*)(hfU + b0);
    const f16x8 Xh1 = *(const f16x8*)(hfU + b1_);
    if (TERMS == 3) {
      const f16x8 Wl = *(const f16x8*)(Abase + chunk * 2048 + 65536);
      const f16x8 Xl0 = *(const f16x8*)(hfU + b0 + 8);
      const f16x8 Xl1 = *(const f16x8*)(hfU + b1_ + 8);
      acc0 = MFMA16(Wh, Xh0, acc0);
      acc0 = MFMA16(Wl, Xh0, acc0);
      acc0 = MFMA16(Wh, Xl0, acc0);
      acc1 = MFMA16(Wh, Xh1, acc1);
      acc1 = MFMA16(Wl, Xh1, acc1);
      acc1 = MFMA16(Wh, Xl1, acc1);
    } else {
      acc0 = MFMA16(Wh, Xh0, acc0);
      acc1 = MFMA16(Wh, Xh1, acc1);
    }
  }
  __syncthreads();                       // S1: all R reads done
#pragma unroll
  for (int q = 0; q < 4; ++q) {
    f16x4 h4a, l4a, h4b, l4b;
#pragma unroll
    for (int e = 0; e < 4; ++e) {
      const int r = q * 4 + e;
      const float bq = bias[w * 32 + 8 * q + 4 * lh + e];
      float v0 = acc0[r] + bq;
      float v1 = acc1[r] + bq;
      if (do_relu) { v0 = fmaxf(v0, 0.f); v1 = fmaxf(v1, 0.f); }
      if (TERMS == 3) {
        u16 hi, lo;
        split_f16(v0, hi, lo); h4a[e] = bits_h(hi); l4a[e] = bits_h(lo);
        split_f16(v1, hi, lo); h4b[e] = bits_h(hi); l4b[e] = bits_h(lo);
      } else {
        h4a[e] = (f16)v0; h4b[e] = (f16)v1;
      }
    }
    const int c = w * 4 + q;
    const int a0 = haddr8(l31, c) + 4 * lh;
    const int a1 = haddr8(32 + l31, c) + 4 * lh;
    *(f16x4*)(hfU + a0) = h4a;
    *(f16x4*)(hfU + a1) = h4b;
    if (TERMS == 3) { *(f16x4*)(hfU + a0 + 8) = l4a; *(f16x4*)(hfU + a1 + 8) = l4b; }
  }
  __syncthreads();                       // S2
}

// ---------------- mindist via Gram matrix G = h h^T (MFMA), h dead afterwards ----------------
__device__ __forceinline__ void mindist_mfma(u16* __restrict__ hfU, float* __restrict__ mindS) {
  const int tid = threadIdx.x;
  const int lane = tid & 63, w = tid >> 6;
  const int gb = w & 3, gi = gb >> 1, gj = gb & 1, ks = w >> 2;
  const int l31 = lane & 31, lh = lane >> 5;
  f32x16 acc = {};
#pragma unroll
  for (int t = 0; t < 8; ++t) {
    const int chunk = 4 * t + 2 * ks + lh;
    const int ra = haddr8(gi * 32 + l31, chunk);
    const int rb_ = haddr8(gj * 32 + l31, chunk);
    const f16x8 ahi = *(const f16x8*)(hfU + ra);
    const f16x8 alo = *(const f16x8*)(hfU + ra + 8);
    const f16x8 bhi = *(const f16x8*)(hfU + rb_);
    const f16x8 blo = *(const f16x8*)(hfU + rb_ + 8);
    acc = MFMA16(ahi, bhi, acc);
    acc = MFMA16(ahi, blo, acc);
    acc = MFMA16(alo, bhi, acc);
  }
  __syncthreads();                       // S1: h dead
  float* hfF = (float*)hfU;
  if (ks == 1) {
#pragma unroll
    for (int r = 0; r < 16; ++r) {
      const int rr = (r & 3) + 8 * (r >> 2) + 4 * lh;
      hfF[gb * 1088 + rr * 34 + l31] = acc[r];
    }
  }
  __syncthreads();                       // S2
  if (ks == 0) {
#pragma unroll
    for (int r = 0; r < 16; ++r) {
      const int rr = (r & 3) + 8 * (r >> 2) + 4 * lh;
      const float g = acc[r] + hfF[gb * 1088 + rr * 34 + l31];
      hfF[8192 + (gi * 32 + rr) * 66 + gj * 32 + l31] = g;
    }
  }
  __syncthreads();                       // S3
  {
    const int i = tid >> 3, jt = tid & 7;
    const float gii = hfF[8192 + i * 66 + i];
    float dmin = 3.4e38f;
#pragma unroll
    for (int jj = 0; jj < 8; ++jj) {
      const int j = jt * 8 + jj;
      const float gjj = hfF[8192 + j * 66 + j];
      const float gij = hfF[8192 + i * 66 + j];
      float d2 = fmaxf(gii + gjj - 2.f * gij, 0.f);
      if (j == i) d2 += 1e9f;
      dmin = fminf(dmin, d2);
    }
    dmin = fminf(dmin, __shfl_xor(dmin, 1));
    dmin = fminf(dmin, __shfl_xor(dmin, 2));
    dmin = fminf(dmin, __shfl_xor(dmin, 4));
    if (jt == 0) mindS[i] = dmin;
  }
  __syncthreads();                       // S4
}

// ---------------- shared staging helpers ----------------
__device__ __forceinline__ void stage_adj(u16* AdjU, const float* AdjF, int b, int tid) {
  const float* src = AdjF + b * 4096;
  for (int t = tid; t < 4096; t += 512)
    AdjU[(t >> 6) * 72 + (t & 63)] = h_bits((f16)src[t]);
}

// xcur = tx * anchor_emb[anchor] + tx. WRITE_LO=false for the output-only (light) phase.
template<bool WRITE_LO>
__device__ __forceinline__ void build_xcur(u16* hfU, const float* h0g, const float* aemb,
                                           const int* anchorS, int b, int tid) {
  const int i = tid >> 3, part = tid & 7;
  const float* t = h0g + (b * 64 + i) * 256;
  const float* e = aemb + anchorS[i] * D_;
#pragma unroll
  for (int c = 0; c < 4; ++c) {
    const int chunk = part * 4 + c;
    const float4 tv0 = *(const float4*)(t + chunk * 8);
    const float4 tv1 = *(const float4*)(t + chunk * 8 + 4);
    const float4 ev0 = *(const float4*)(e + chunk * 8);
    const float4 ev1 = *(const float4*)(e + chunk * 8 + 4);
    float vv[8];
    vv[0] = fmaf(tv0.x, ev0.x, tv0.x); vv[1] = fmaf(tv0.y, ev0.y, tv0.y);
    vv[2] = fmaf(tv0.z, ev0.z, tv0.z); vv[3] = fmaf(tv0.w, ev0.w, tv0.w);
    vv[4] = fmaf(tv1.x, ev1.x, tv1.x); vv[5] = fmaf(tv1.y, ev1.y, tv1.y);
    vv[6] = fmaf(tv1.z, ev1.z, tv1.z); vv[7] = fmaf(tv1.w, ev1.w, tv1.w);
    f16x8 hi8, lo8;
#pragma unroll
    for (int ee = 0; ee < 8; ++ee) { u16 h, l; split_f16(vv[ee], h, l); hi8[ee] = bits_h(h); lo8[ee] = bits_h(l); }
    const int a = haddr8(i, chunk);
    *(f16x8*)(hfU + a) = hi8;
    if (WRITE_LO) *(f16x8*)(hfU + a + 8) = lo8;
  }
}

// Gumbel-argmax sampling (exact JAX threefry); updates anchorS. Call with all threads; sync outside.
__device__ __forceinline__ void sample_anchor(const float* mindS, float* scoreS, int* anchorS,
                                              int m, int b, int iter, int tid) {
  if (tid < 64) {
    const int j = tid;
    uint32_t k0, k1;
    threefry2x32(0u, 42u, 0u, (uint32_t)iter, k0, k1);
    const uint32_t p = (uint32_t)(m * (B_ * NPG_) + b * NPG_ + j);
    uint32_t o0, o1, bits;
    if (p < 32768u) { threefry2x32(k0, k1, p, p + 32768u, o0, o1); bits = o0; }
    else            { threefry2x32(k0, k1, p - 32768u, p, o0, o1); bits = o1; }
    const float f = __uint_as_float((bits >> 9) | 0x3f800000u) - 1.0f;
    const float uv = fmaxf(1e-9f, f + 1e-9f);
    const float pred = -mindS[j] - ((anchorS[j] > 0) ? 10.0f : 0.0f);
    scoreS[j] = pred - logf(-logf(uv));
  }
  __syncthreads();
  if (tid == 0) {
    int best = 0; float bv = scoreS[0];
    for (int j = 1; j < 64; ++j) { const float v = scoreS[j]; if (v > bv) { bv = v; best = j; } }
    anchorS[best] = iter;
  }
}

// ---------------- small kernels ----------------
__global__ void build_adj_kernel(const int* __restrict__ esrc, const int* __restrict__ edst,
                                 float* __restrict__ AdjF) {
  const int e = blockIdx.x * 256 + threadIdx.x;
  if (e < E_) {
    const int s = esrc[e];
    const int d = edst[e];
    const int g = s >> 6;
    atomicAdd(AdjF + g * 4096 + (d & 63) * 64 + (s & 63), 1.0f);
  }
}

// Pre-split W (f16 hi/lo): off = (k>>3)*2048 + col*8 + (k&7); lo plane at +65536.
__global__ __launch_bounds__(256) void prep_wt(const float* __restrict__ gW1, const float* __restrict__ gW2,
                                               const float* __restrict__ Wn2n, u16* __restrict__ WTbuf) {
  const int mat = blockIdx.x;
  const float* Wsrc = (mat < 5) ? (gW1 + mat * 65536)
                    : (mat < 10) ? (gW2 + (mat - 5) * 65536) : Wn2n;
  u16* dst = WTbuf + (size_t)mat * 131072;
  const int base = blockIdx.y * 2048;
  for (int idx = base + threadIdx.x; idx < base + 2048; idx += 256) {
    const int k = idx >> 8, d = idx & 255;
    const float a = Wsrc[idx];
    u16 hi, lo; split_f16(a, hi, lo);
    const int off = (k >> 3) * 2048 + d * 8 + (k & 7);
    dst[off] = hi;
    dst[65536 + off] = lo;
  }
}

// ---------------- phase 1: encoder + iter-1 GNN + mindist, m-invariant -> once per b ----------------
__global__ __launch_bounds__(512)
void gnn1_kernel(const float* __restrict__ x, const float* __restrict__ Wenc,
                 const float* __restrict__ benc, float* __restrict__ h0g,
                 const float* __restrict__ AdjF, const u16* __restrict__ WTbuf,
                 const float* __restrict__ gb1, const float* __restrict__ gb2,
                 const float* __restrict__ eps, float* __restrict__ mindG) {
  __shared__ __align__(16) u16 hfU[256 * TROW];   // R (64x520) / T (256x136) ping-pong region
  __shared__ __align__(16) u16 AdjU[64 * 72];
  __shared__ float mindS[64];
  __shared__ float diagC[64];
  __shared__ int flagS;
  const int tid = threadIdx.x;
  const int b = blockIdx.x;

  // --- fused encoder: h0 = relu(x @ Wenc + benc) for this graph's 64 nodes ---
  // Wenc staged padded with ROW STRIDE 264 (max intra-row offset 255+7=262 < 264;
  // R8's stride 260 made rows overlap -> 3 corrupted weight columns -> argmax flip).
  {
    float* scr = (float*)hfU;                 // [0..4223) Wenc, [4300..4556) benc, [4600..5624) x
    for (int t = tid; t < 4096; t += 512) {
      const int k = t >> 8, d = t & 255;
      scr[k * 264 + d + (d >> 5)] = Wenc[t];
    }
    if (tid < 256) scr[4300 + tid] = benc[tid];
    for (int t = tid; t < 1024; t += 512) scr[4600 + t] = x[b * 1024 + t];
    __syncthreads();

    const int i = tid >> 3, part = tid & 7;
    float xv[16];
#pragma unroll
    for (int k = 0; k < 16; ++k) xv[k] = scr[4600 + i * 16 + k];
    float hv[32];
#pragma unroll
    for (int dd = 0; dd < 32; ++dd) {
      const int d = part * 32 + dd;
      float acc = scr[4300 + d];
#pragma unroll
      for (int k = 0; k < 16; ++k) acc = fmaf(xv[k], scr[k * 264 + d + (d >> 5)], acc);
      hv[dd] = fmaxf(acc, 0.f);
    }
    // write h0g (coalesced float4) for mega's build_xcur
    float* dst = h0g + (b * 64 + i) * 256 + part * 32;
#pragma unroll
    for (int dd = 0; dd < 32; dd += 4) {
      float4 v; v.x = hv[dd]; v.y = hv[dd + 1]; v.z = hv[dd + 2]; v.w = hv[dd + 3];
      *(float4*)(dst + dd) = v;
    }
    __syncthreads();                          // scratch reads done before u16 writes
    // split-write h0 into hfU (R layout) from registers
#pragma unroll
    for (int c = 0; c < 4; ++c) {
      f16x8 hi8, lo8;
#pragma unroll
      for (int e = 0; e < 8; ++e) { u16 h, l; split_f16(hv[c * 8 + e], h, l); hi8[e] = bits_h(h); lo8[e] = bits_h(l); }
      const int a = haddr8(i, part * 4 + c);
      *(f16x8*)(hfU + a) = hi8;
      *(f16x8*)(hfU + a + 8) = lo8;
    }
  }
  stage_adj(AdjU, AdjF, b, tid);
  if (tid == 0) flagS = 0;
  if (tid < 64) {
    const float dc = AdjF[b * 4096 + tid * 65];
    diagC[tid] = dc;
    int f = 0;
    for (int l = 0; l < L_; ++l) {
      const float v = dc + 1.0f + eps[l];
      if (h2f(h_bits((f16)v)) != v) f = 1;
    }
    if (f) atomicOr(&flagS, 1);
  }
  __syncthreads();
  const int slow = flagS;

  for (int l = 0; l < L_; ++l) {
    const float epsl = 1.0f + eps[l];
    if (tid < 64) AdjU[tid * 72 + tid] = h_bits((f16)(diagC[tid] + epsl));  // A' diag (pub. by G1 barriers)
    gemm_w_RT<3>(hfU, WTbuf + (size_t)l * 131072, nullptr, false);
    gemm_adj_TR<3>(hfU, AdjU, gb1 + l * D_, slow, diagC, epsl);
    gemm_w_RR<3>(hfU, WTbuf + (size_t)(5 + l) * 131072, gb2 + l * D_, true);
  }
  mindist_mfma(hfU, mindS);
  if (tid < 64) mindG[b * 64 + tid] = mindS[tid];
}

// ---------------- phase 2: per (b,m) — sample a1, iters 2..3, head ----------------
__global__ __launch_bounds__(512, 4)
void mega_kernel(const float* __restrict__ h0g, const float* __restrict__ AdjF,
                 const u16* __restrict__ WTbuf,
                 const float* __restrict__ gb1, const float* __restrict__ gb2,
                 const float* __restrict__ eps, const float* __restrict__ aemb,
                 const float* __restrict__ bn2n,
                 const float* __restrict__ Wpred, const float* __restrict__ bpred,
                 const float* __restrict__ mindG, float* __restrict__ outp) {
  __shared__ __align__(16) u16 hfU[256 * TROW];   // 69632 B R/T ping-pong (also scratch when dead)
  __shared__ __align__(16) u16 AdjU[64 * 72];     //  9216 B f16 adjacency (diag = cnt+1+eps)
  __shared__ float mindS[64];
  __shared__ float scoreS[64];
  __shared__ float hgS[256];
  __shared__ int   anchorS[64];
  __shared__ float diagC[64];
  __shared__ int   flagS;

  const int tid = threadIdx.x;
  const int b = blockIdx.x;
  const int m = blockIdx.y;

  stage_adj(AdjU, AdjF, b, tid);
  if (tid == 0) flagS = 0;
  if (tid < 64) {
    anchorS[tid] = 0;
    mindS[tid] = mindG[b * 64 + tid];
    const float dc = AdjF[b * 4096 + tid * 65];
    diagC[tid] = dc;
    int f = 0;
    for (int l = 0; l < L_; ++l) {
      const float v = dc + 1.0f + eps[l];
      if (h2f(h_bits((f16)v)) != v) f = 1;
    }
    if (f) atomicOr(&flagS, 1);
  }
  __syncthreads();

  // iter-1 sampling from precomputed mindist
  sample_anchor(mindS, scoreS, anchorS, m, b, 1, tid);
  __syncthreads();
  build_xcur<true>(hfU, h0g, aemb, anchorS, b, tid);
  __syncthreads();

  const int slow = flagS;

  // ----- iter 2: full-precision GNN (feeds argmax) -----
  for (int l = 0; l < L_; ++l) {
    const float epsl = 1.0f + eps[l];
    if (tid < 64) AdjU[tid * 72 + tid] = h_bits((f16)(diagC[tid] + epsl));
    gemm_w_RT<3>(hfU, WTbuf + (size_t)l * 131072, nullptr, false);
    gemm_adj_TR<3>(hfU, AdjU, gb1 + l * D_, slow, diagC, epsl);
    gemm_w_RR<3>(hfU, WTbuf + (size_t)(5 + l) * 131072, gb2 + l * D_, true);
  }
  mindist_mfma(hfU, mindS);
  sample_anchor(mindS, scoreS, anchorS, m, b, 2, tid);
  __syncthreads();
  build_xcur<false>(hfU, h0g, aemb, anchorS, b, tid);   // light phase: hi plane only
  __syncthreads();

  // ----- iter 3: output-path GNN, 1-term f16 hi-only (tolerance is bf16-scale) -----
  for (int l = 0; l < L_; ++l) {
    const float epsl = 1.0f + eps[l];
    if (tid < 64) AdjU[tid * 72 + tid] = h_bits((f16)(diagC[tid] + epsl));
    gemm_w_RT<1>(hfU, WTbuf + (size_t)l * 131072, nullptr, false);
    gemm_adj_TR<1>(hfU, AdjU, gb1 + l * D_, slow, diagC, epsl);
    gemm_w_RR<1>(hfU, WTbuf + (size_t)(5 + l) * 131072, gb2 + l * D_, true);
  }

  // ----- head: hn = relu(h @ W_n2n + b_n2n) (form A, R->T), mean over nodes from T rows -----
  gemm_w_RT<1>(hfU, WTbuf + (size_t)10 * 131072, bn2n, true);
  if (tid < 256) {
    float s = 0.f;
#pragma unroll
    for (int c = 0; c < 8; ++c) {
      const f16x8 v = *(const f16x8*)(hfU + taddr8(tid, c));
      s += (float)v[0] + (float)v[1] + (float)v[2] + (float)v[3]
         + (float)v[4] + (float)v[5] + (float)v[6] + (float)v[7];
    }
    hgS[tid] = s * (1.0f / 64.0f);
  }
  __syncthreads();
  if (tid < 160) {
    const int t = tid >> 4, part = tid & 15;
    float s = 0.f;
    for (int d = part * 16; d < part * 16 + 16; ++d) s = fmaf(hgS[d], Wpred[d * TASKS_ + t], s);
    s += __shfl_xor(s, 1); s += __shfl_xor(s, 2); s += __shfl_xor(s, 4); s += __shfl_xor(s, 8);
    if (part == 0) {
      float val = s * 0.25f;
      if (m == 0) val += bpred[t];
      atomicAdd(outp + b * TASKS_ + t, val);
    }
  }
}

// ---------------- launch ----------------
extern "C" void kernel_launch(void* const* d_in, const int* in_sizes, int n_in,
                              void* d_out, int out_size, void* d_ws, size_t ws_size,
                              hipStream_t stream) {
  const float* x     = (const float*)d_in[0];
  const float* Wenc  = (const float*)d_in[1];
  const float* benc  = (const float*)d_in[2];
  const float* gW1   = (const float*)d_in[3];
  const float* gb1   = (const float*)d_in[4];
  const float* gW2   = (const float*)d_in[5];
  const float* gb2   = (const float*)d_in[6];
  const float* eps   = (const float*)d_in[7];
  const float* aemb  = (const float*)d_in[8];
  const float* Wn2n  = (const float*)d_in[9];
  const float* bn2n  = (const float*)d_in[10];
  const float* Wpred = (const float*)d_in[11];
  const float* bpred = (const float*)d_in[12];
  const int* esrc    = (const int*)d_in[13];
  const int* edst    = (const int*)d_in[14];
  float* outp = (float*)d_out;

  float* h0g  = (float*)d_ws;                      // 16 MB
  float* AdjF = h0g + (size_t)N_ * D_;             // 4 MB
  u16* WTbuf  = (u16*)(AdjF + B_ * 4096);          // 11 * 256 KB f16 split weights
  float* mindG = (float*)(WTbuf + (size_t)11 * 131072);   // B*64 floats

  hipMemsetAsync(AdjF, 0, (size_t)B_ * 4096 * sizeof(float), stream);
  hipMemsetAsync(outp, 0, (size_t)out_size * sizeof(float), stream);
  build_adj_kernel<<<dim3((E_ + 255) / 256), dim3(256), 0, stream>>>(esrc, edst, AdjF);
  prep_wt<<<dim3(11, 32), dim3(256), 0, stream>>>(gW1, gW2, Wn2n, WTbuf);
  gnn1_kernel<<<dim3(B_), dim3(512), 0, stream>>>(x, Wenc, benc, h0g, AdjF, WTbuf,
                                                  gb1, gb2, eps, mindG);
  mega_kernel<<<dim3(B_, M_), dim3(512), 0, stream>>>(h0g, AdjF, WTbuf, gb1, gb2,
                                                      eps, aemb, bn2n, Wpred, bpred, mindG, outp);
}

// Round 2
// 579.072 us; speedup vs baseline: 1.1740x; 1.1740x over previous
//
#include <hip/hip_runtime.h>
#include <stdint.h>

typedef unsigned short u16;
typedef _Float16 f16;
typedef f16 f16x4 __attribute__((ext_vector_type(4)));
typedef f16 f16x8 __attribute__((ext_vector_type(8)));
typedef float f32x16 __attribute__((ext_vector_type(16)));

// Problem constants
#define M_     4
#define B_     256
#define NPG_   64
#define N_     (B_*NPG_)    // 16384
#define DEG_   8
#define E_     (N_*DEG_)    // 131072
#define DF_    16
#define D_     256
#define L_     5
#define NA_    2
#define TASKS_ 10

// R10: software-pipelined operand prefetch (LDS dist-1, global dist-2) + setprio
// around MFMA clusters. R9 showed latency-bound (VGPR=64 -> no hoisting; both
// pipes <35% busy; MFMA floor ~39us vs 520us measured).
#define HROW 520            // u16 row stride of node-major split-h (1040 B, 16B aligned)
#define TROW 136            // u16 row stride of feature-major split-u (272 B, 16B aligned)
#define MFMA16(a,b,c) __builtin_amdgcn_mfma_f32_32x32x16_f16(a,b,c,0,0,0)

// ---------------- f16 helpers ----------------
__device__ __forceinline__ u16 h_bits(f16 h) { union { f16 h; u16 u; } c; c.h = h; return c.u; }
__device__ __forceinline__ f16 bits_h(u16 u) { union { u16 u; f16 h; } c; c.u = u; return c.h; }
__device__ __forceinline__ float h2f(u16 u) { return (float)bits_h(u); }
__device__ __forceinline__ void split_f16(float v, u16& hi, u16& lo) {
  f16 h = (f16)v;
  f16 l = (f16)(v - (float)h);
  hi = h_bits(h); lo = h_bits(l);
}

// R layout: u16 index of the 8-elem hi group for (node row, feature chunk); lo group at +8.
__device__ __forceinline__ int haddr8(int row, int chunk) {
  return row * HROW + ((chunk ^ (row & 7)) << 4);
}
// T layout: u16 index of the 8-elem hi group for (feature row d, node chunk c); lo group at +8.
__device__ __forceinline__ int taddr8(int d, int c) {
  return d * TROW + ((c ^ (d & 7)) << 4);
}

// ---------------- Threefry-2x32 (exact JAX semantics) ----------------
__device__ __forceinline__ uint32_t rotl32(uint32_t v, int r) { return (v << r) | (v >> (32 - r)); }
__device__ __forceinline__ void threefry2x32(uint32_t k0, uint32_t k1, uint32_t x0, uint32_t x1,
                                             uint32_t& o0, uint32_t& o1) {
  const uint32_t ks2 = k0 ^ k1 ^ 0x1BD11BDAu;
  x0 += k0; x1 += k1;
#define TFR(r) { x0 += x1; x1 = rotl32(x1, r); x1 ^= x0; }
  TFR(13) TFR(15) TFR(26) TFR(6)   x0 += k1;  x1 += ks2 + 1u;
  TFR(17) TFR(29) TFR(16) TFR(24)  x0 += ks2; x1 += k0 + 2u;
  TFR(13) TFR(15) TFR(26) TFR(6)   x0 += k0;  x1 += k1 + 3u;
  TFR(17) TFR(29) TFR(16) TFR(24)  x0 += k1;  x1 += ks2 + 4u;
  TFR(13) TFR(15) TFR(26) TFR(6)   x0 += ks2; x1 += k0 + 5u;
#undef TFR
  o0 = x0; o1 = x1;
}

// ---------------- G1 (form A): out = in @ W (+bias, relu) ; reads R, writes T ----------------
// Pipelined: A (LDS) prefetch dist 1, B (global/L2) prefetch dist 2.
template<int TERMS>
__device__ __forceinline__ void gemm_w_RT(u16* __restrict__ hfU, const u16* __restrict__ WTm,
                                          const float* __restrict__ bias, bool do_relu) {
  const int tid = threadIdx.x;
  const int lane = tid & 63, w = tid >> 6;
  const int l31 = lane & 31, lh = lane >> 5;
  const int col = w * 32 + l31;
  const float bv = bias ? bias[col] : 0.f;
  f32x16 acc0 = {}, acc1 = {};
  const u16* Bbase = WTm + col * 8;

  f16x8 ah0[2], ah1[2], al0[2], al1[2];   // LDS A stages
  f16x8 bh[3], bl[3];                     // global B stages
  auto ldA = [&](int ks, int s) {
    const int chunk = ks * 2 + lh;
    const int a0 = haddr8(l31, chunk);
    const int a1 = haddr8(32 + l31, chunk);
    ah0[s] = *(const f16x8*)(hfU + a0);
    ah1[s] = *(const f16x8*)(hfU + a1);
    if (TERMS == 3) {
      al0[s] = *(const f16x8*)(hfU + a0 + 8);
      al1[s] = *(const f16x8*)(hfU + a1 + 8);
    }
  };
  auto ldB = [&](int ks, int s) {
    const int chunk = ks * 2 + lh;
    bh[s] = *(const f16x8*)(Bbase + chunk * 2048);
    if (TERMS == 3) bl[s] = *(const f16x8*)(Bbase + chunk * 2048 + 65536);
  };
  ldB(0, 0); ldB(1, 1); ldA(0, 0);
#pragma unroll
  for (int ks = 0; ks < 16; ++ks) {
    if (ks < 15) ldA(ks + 1, (ks + 1) & 1);
    if (ks < 14) ldB(ks + 2, (ks + 2) % 3);
    const int s = ks & 1, t = ks % 3;
    __builtin_amdgcn_s_setprio(1);
    if (TERMS == 3) {
      acc0 = MFMA16(ah0[s], bh[t], acc0);
      acc0 = MFMA16(ah0[s], bl[t], acc0);
      acc0 = MFMA16(al0[s], bh[t], acc0);
      acc1 = MFMA16(ah1[s], bh[t], acc1);
      acc1 = MFMA16(ah1[s], bl[t], acc1);
      acc1 = MFMA16(al1[s], bh[t], acc1);
    } else {
      acc0 = MFMA16(ah0[s], bh[t], acc0);
      acc1 = MFMA16(ah1[s], bh[t], acc1);
    }
    __builtin_amdgcn_s_setprio(0);
  }
  __syncthreads();                       // S1: all R reads done, region dead
  // C frag: node row rr=(r&3)+8q+4lh, col fixed -> T rows are node-runs-of-4 -> b64 writes
#pragma unroll
  for (int q = 0; q < 4; ++q) {
    f16x4 h4a, l4a, h4b, l4b;
#pragma unroll
    for (int e = 0; e < 4; ++e) {
      float v0 = acc0[q * 4 + e] + bv;
      float v1 = acc1[q * 4 + e] + bv;
      if (do_relu) { v0 = fmaxf(v0, 0.f); v1 = fmaxf(v1, 0.f); }
      if (TERMS == 3) {
        u16 hi, lo;
        split_f16(v0, hi, lo); h4a[e] = bits_h(hi); l4a[e] = bits_h(lo);
        split_f16(v1, hi, lo); h4b[e] = bits_h(hi); l4b[e] = bits_h(lo);
      } else {
        h4a[e] = (f16)v0; h4b[e] = (f16)v1;
      }
    }
    const int t0 = taddr8(col, q) + 4 * lh;       // nodes 8q+4lh..+3
    const int t1 = taddr8(col, 4 + q) + 4 * lh;   // nodes 32+...
    *(f16x4*)(hfU + t0) = h4a;
    *(f16x4*)(hfU + t1) = h4b;
    if (TERMS == 3) { *(f16x4*)(hfU + t0 + 8) = l4a; *(f16x4*)(hfU + t1 + 8) = l4b; }
  }
  __syncthreads();                       // S2: T ready
}

// ---------------- G2: z = relu(A' @ u + b1), A' = Adj + (1+eps)I ; reads T, writes R ----------
// All-LDS operands: prefetch dist 1.
template<int TERMS>
__device__ __forceinline__ void gemm_adj_TR(u16* __restrict__ hfU, const u16* __restrict__ AdjU,
                                            const float* __restrict__ bias, int slow,
                                            const float* __restrict__ diagC, float epsl) {
  const int tid = threadIdx.x;
  const int lane = tid & 63, w = tid >> 6;
  const int l31 = lane & 31, lh = lane >> 5;
  const int drow = w * 32 + l31;          // T row (feature) this lane feeds as A
  f32x16 acc0 = {}, acc1 = {};

  f16x8 uh[2], ul[2], B0[2], B1[2];
  auto ld = [&](int kk, int s) {
    const int chunk = kk * 2 + lh;
    const int ta = taddr8(drow, chunk);
    uh[s] = *(const f16x8*)(hfU + ta);
    if (TERMS == 3) ul[s] = *(const f16x8*)(hfU + ta + 8);
    B0[s] = *(const f16x8*)(AdjU + l31 * 72 + chunk * 8);
    B1[s] = *(const f16x8*)(AdjU + (32 + l31) * 72 + chunk * 8);
  };
  ld(0, 0);
#pragma unroll
  for (int kk = 0; kk < 4; ++kk) {
    if (kk < 3) ld(kk + 1, (kk + 1) & 1);
    const int s = kk & 1;
    __builtin_amdgcn_s_setprio(1);
    acc0 = MFMA16(uh[s], B0[s], acc0);
    acc1 = MFMA16(uh[s], B1[s], acc1);
    if (TERMS == 3) {
      acc0 = MFMA16(ul[s], B0[s], acc0);
      acc1 = MFMA16(ul[s], B1[s], acc1);
    }
    __builtin_amdgcn_s_setprio(0);
  }
  // exact-diag correction — only when (1+eps) is not f16-exact (never for eps=0 inputs)
  if (slow) {
    const int i0 = l31, i1 = 32 + l31;
    const float v0d = diagC[i0] + epsl, v1d = diagC[i1] + epsl;
    const float r0 = v0d - h2f(h_bits((f16)v0d));
    const float r1 = v1d - h2f(h_bits((f16)v1d));
#pragma unroll
    for (int r = 0; r < 16; ++r) {
      const int dp = w * 32 + (r & 3) + 8 * (r >> 2) + 4 * lh;
      const int a0 = taddr8(dp, i0 >> 3) + (i0 & 7);
      const int a1 = taddr8(dp, i1 >> 3) + (i1 & 7);
      float u0 = h2f(hfU[a0]);
      float u1 = h2f(hfU[a1]);
      if (TERMS == 3) { u0 += h2f(hfU[a0 + 8]); u1 += h2f(hfU[a1 + 8]); }
      acc0[r] += r0 * u0;
      acc1[r] += r1 * u1;
    }
  }
  __syncthreads();                       // S1: all T reads done
  // C frag: col = node i (l31 / 32+l31), rows = d-runs-of-4 -> R writes are b64
#pragma unroll
  for (int q = 0; q < 4; ++q) {
    f16x4 h4a, l4a, h4b, l4b;
#pragma unroll
    for (int e = 0; e < 4; ++e) {
      const int r = q * 4 + e;
      const float bq = bias[w * 32 + 8 * q + 4 * lh + e];
      float v0 = fmaxf(acc0[r] + bq, 0.f);
      float v1 = fmaxf(acc1[r] + bq, 0.f);
      if (TERMS == 3) {
        u16 hi, lo;
        split_f16(v0, hi, lo); h4a[e] = bits_h(hi); l4a[e] = bits_h(lo);
        split_f16(v1, hi, lo); h4b[e] = bits_h(hi); l4b[e] = bits_h(lo);
      } else {
        h4a[e] = (f16)v0; h4b[e] = (f16)v1;
      }
    }
    const int c = w * 4 + q;
    const int a0 = haddr8(l31, c) + 4 * lh;
    const int a1 = haddr8(32 + l31, c) + 4 * lh;
    *(f16x4*)(hfU + a0) = h4a;
    *(f16x4*)(hfU + a1) = h4b;
    if (TERMS == 3) { *(f16x4*)(hfU + a0 + 8) = l4a; *(f16x4*)(hfU + a1 + 8) = l4b; }
  }
  __syncthreads();                       // S2: R ready
}

// ---------------- G3 (form B): out = in @ W (+bias, relu) ; reads R, writes R ----------------
// Computes out^T = W^T @ in^T: A = W^T rows (global, dist 2), B = in rows (LDS, dist 1).
template<int TERMS>
__device__ __forceinline__ void gemm_w_RR(u16* __restrict__ hfU, const u16* __restrict__ WTm,
                                          const float* __restrict__ bias, bool do_relu) {
  const int tid = threadIdx.x;
  const int lane = tid & 63, w = tid >> 6;
  const int l31 = lane & 31, lh = lane >> 5;
  f32x16 acc0 = {}, acc1 = {};
  const u16* Abase = WTm + (w * 32 + l31) * 8;   // W^T row d' = w*32+l31

  f16x8 Wh[3], Wl[3];                     // global A stages
  f16x8 Xh0[2], Xh1[2], Xl0[2], Xl1[2];   // LDS B stages
  auto ldW = [&](int ks, int s) {
    const int chunk = ks * 2 + lh;
    Wh[s] = *(const f16x8*)(Abase + chunk * 2048);
    if (TERMS == 3) Wl[s] = *(const f16x8*)(Abase + chunk * 2048 + 65536);
  };
  auto ldX = [&](int ks, int s) {
    const int chunk = ks * 2 + lh;
    const int b0 = haddr8(l31, chunk);
    const int b1_ = haddr8(32 + l31, chunk);
    Xh0[s] = *(const f16x8*)(hfU + b0);
    Xh1[s] = *(const f16x8*)(hfU + b1_);
    if (TERMS == 3) {
      Xl0[s] = *(const f16x8*)(hfU + b0 + 8);
      Xl1[s] = *(const f16x8*)(hfU + b1_ + 8);
    }
  };
  ldW(0, 0); ldW(1, 1); ldX(0, 0);
#pragma unroll
  for (int ks = 0; ks < 16; ++ks) {
    if (ks < 15) ldX(ks + 1, (ks + 1) & 1);
    if (ks < 14) ldW(ks + 2, (ks + 2) % 3);
    const int s = ks & 1, t = ks % 3;
    __builtin_amdgcn_s_setprio(1);
    if (TERMS == 3) {
      acc0 = MFMA16(Wh[t], Xh0[s], acc0);
      acc0 = MFMA16(Wl[t], Xh0[s], acc0);
      acc0 = MFMA16(Wh[t], Xl0[s], acc0);
      acc1 = MFMA16(Wh[t], Xh1[s], acc1);
      acc1 = MFMA16(Wl[t], Xh1[s], acc1);
      acc1 = MFMA16(Wh[t], Xl1[s], acc1);
    } else {
      acc0 = MFMA16(Wh[t], Xh0[s], acc0);
      acc1 = MFMA16(Wh[t], Xh1[s], acc1);
    }
    __builtin_amdgcn_s_setprio(0);
  }
  __syncthreads();                       // S1: all R reads done
#pragma unroll
  for (int q = 0; q < 4; ++q) {
    f16x4 h4a, l4a, h4b, l4b;
#pragma unroll
    for (int e = 0; e < 4; ++e) {
      const int r = q * 4 + e;
      const float bq = bias[w * 32 + 8 * q + 4 * lh + e];
      float v0 = acc0[r] + bq;
      float v1 = acc1[r] + bq;
      if (do_relu) { v0 = fmaxf(v0, 0.f); v1 = fmaxf(v1, 0.f); }
      if (TERMS == 3) {
        u16 hi, lo;
        split_f16(v0, hi, lo); h4a[e] = bits_h(hi); l4a[e] = bits_h(lo);
        split_f16(v1, hi, lo); h4b[e] = bits_h(hi); l4b[e] = bits_h(lo);
      } else {
        h4a[e] = (f16)v0; h4b[e] = (f16)v1;
      }
    }
    const int c = w * 4 + q;
    const int a0 = haddr8(l31, c) + 4 * lh;
    const int a1 = haddr8(32 + l31, c) + 4 * lh;
    *(f16x4*)(hfU + a0) = h4a;
    *(f16x4*)(hfU + a1) = h4b;
    if (TERMS == 3) { *(f16x4*)(hfU + a0 + 8) = l4a; *(f16x4*)(hfU + a1 + 8) = l4b; }
  }
  __syncthreads();                       // S2
}

// ---------------- mindist via Gram matrix G = h h^T (MFMA), h dead afterwards ----------------
__device__ __forceinline__ void mindist_mfma(u16* __restrict__ hfU, float* __restrict__ mindS) {
  const int tid = threadIdx.x;
  const int lane = tid & 63, w = tid >> 6;
  const int gb = w & 3, gi = gb >> 1, gj = gb & 1, ks = w >> 2;
  const int l31 = lane & 31, lh = lane >> 5;
  f32x16 acc = {};

  f16x8 Ah[2], Al[2], Bh[2], Bl[2];
  auto ld = [&](int t, int s) {
    const int chunk = 4 * t + 2 * ks + lh;
    const int ra = haddr8(gi * 32 + l31, chunk);
    const int rb_ = haddr8(gj * 32 + l31, chunk);
    Ah[s] = *(const f16x8*)(hfU + ra);
    Al[s] = *(const f16x8*)(hfU + ra + 8);
    Bh[s] = *(const f16x8*)(hfU + rb_);
    Bl[s] = *(const f16x8*)(hfU + rb_ + 8);
  };
  ld(0, 0);
#pragma unroll
  for (int t = 0; t < 8; ++t) {
    if (t < 7) ld(t + 1, (t + 1) & 1);
    const int s = t & 1;
    __builtin_amdgcn_s_setprio(1);
    acc = MFMA16(Ah[s], Bh[s], acc);
    acc = MFMA16(Ah[s], Bl[s], acc);
    acc = MFMA16(Al[s], Bh[s], acc);
    __builtin_amdgcn_s_setprio(0);
  }
  __syncthreads();                       // S1: h dead
  float* hfF = (float*)hfU;
  if (ks == 1) {
#pragma unroll
    for (int r = 0; r < 16; ++r) {
      const int rr = (r & 3) + 8 * (r >> 2) + 4 * lh;
      hfF[gb * 1088 + rr * 34 + l31] = acc[r];
    }
  }
  __syncthreads();                       // S2
  if (ks == 0) {
#pragma unroll
    for (int r = 0; r < 16; ++r) {
      const int rr = (r & 3) + 8 * (r >> 2) + 4 * lh;
      const float g = acc[r] + hfF[gb * 1088 + rr * 34 + l31];
      hfF[8192 + (gi * 32 + rr) * 66 + gj * 32 + l31] = g;
    }
  }
  __syncthreads();                       // S3
  {
    const int i = tid >> 3, jt = tid & 7;
    const float gii = hfF[8192 + i * 66 + i];
    float dmin = 3.4e38f;
#pragma unroll
    for (int jj = 0; jj < 8; ++jj) {
      const int j = jt * 8 + jj;
      const float gjj = hfF[8192 + j * 66 + j];
      const float gij = hfF[8192 + i * 66 + j];
      float d2 = fmaxf(gii + gjj - 2.f * gij, 0.f);
      if (j == i) d2 += 1e9f;
      dmin = fminf(dmin, d2);
    }
    dmin = fminf(dmin, __shfl_xor(dmin, 1));
    dmin = fminf(dmin, __shfl_xor(dmin, 2));
    dmin = fminf(dmin, __shfl_xor(dmin, 4));
    if (jt == 0) mindS[i] = dmin;
  }
  __syncthreads();                       // S4
}

// ---------------- shared staging helpers ----------------
__device__ __forceinline__ void stage_adj(u16* AdjU, const float* AdjF, int b, int tid) {
  const float* src = AdjF + b * 4096;
  for (int t = tid; t < 4096; t += 512)
    AdjU[(t >> 6) * 72 + (t & 63)] = h_bits((f16)src[t]);
}

// xcur = tx * anchor_emb[anchor] + tx. WRITE_LO=false for the output-only (light) phase.
template<bool WRITE_LO>
__device__ __forceinline__ void build_xcur(u16* hfU, const float* h0g, const float* aemb,
                                           const int* anchorS, int b, int tid) {
  const int i = tid >> 3, part = tid & 7;
  const float* t = h0g + (b * 64 + i) * 256;
  const float* e = aemb + anchorS[i] * D_;
#pragma unroll
  for (int c = 0; c < 4; ++c) {
    const int chunk = part * 4 + c;
    const float4 tv0 = *(const float4*)(t + chunk * 8);
    const float4 tv1 = *(const float4*)(t + chunk * 8 + 4);
    const float4 ev0 = *(const float4*)(e + chunk * 8);
    const float4 ev1 = *(const float4*)(e + chunk * 8 + 4);
    float vv[8];
    vv[0] = fmaf(tv0.x, ev0.x, tv0.x); vv[1] = fmaf(tv0.y, ev0.y, tv0.y);
    vv[2] = fmaf(tv0.z, ev0.z, tv0.z); vv[3] = fmaf(tv0.w, ev0.w, tv0.w);
    vv[4] = fmaf(tv1.x, ev1.x, tv1.x); vv[5] = fmaf(tv1.y, ev1.y, tv1.y);
    vv[6] = fmaf(tv1.z, ev1.z, tv1.z); vv[7] = fmaf(tv1.w, ev1.w, tv1.w);
    f16x8 hi8, lo8;
#pragma unroll
    for (int ee = 0; ee < 8; ++ee) { u16 h, l; split_f16(vv[ee], h, l); hi8[ee] = bits_h(h); lo8[ee] = bits_h(l); }
    const int a = haddr8(i, chunk);
    *(f16x8*)(hfU + a) = hi8;
    if (WRITE_LO) *(f16x8*)(hfU + a + 8) = lo8;
  }
}

// Gumbel-argmax sampling (exact JAX threefry); updates anchorS. Call with all threads; sync outside.
__device__ __forceinline__ void sample_anchor(const float* mindS, float* scoreS, int* anchorS,
                                              int m, int b, int iter, int tid) {
  if (tid < 64) {
    const int j = tid;
    uint32_t k0, k1;
    threefry2x32(0u, 42u, 0u, (uint32_t)iter, k0, k1);
    const uint32_t p = (uint32_t)(m * (B_ * NPG_) + b * NPG_ + j);
    uint32_t o0, o1, bits;
    if (p < 32768u) { threefry2x32(k0, k1, p, p + 32768u, o0, o1); bits = o0; }
    else            { threefry2x32(k0, k1, p - 32768u, p, o0, o1); bits = o1; }
    const float f = __uint_as_float((bits >> 9) | 0x3f800000u) - 1.0f;
    const float uv = fmaxf(1e-9f, f + 1e-9f);
    const float pred = -mindS[j] - ((anchorS[j] > 0) ? 10.0f : 0.0f);
    scoreS[j] = pred - logf(-logf(uv));
  }
  __syncthreads();
  if (tid == 0) {
    int best = 0; float bv = scoreS[0];
    for (int j = 1; j < 64; ++j) { const float v = scoreS[j]; if (v > bv) { bv = v; best = j; } }
    anchorS[best] = iter;
  }
}

// ---------------- small kernels ----------------
__global__ void build_adj_kernel(const int* __restrict__ esrc, const int* __restrict__ edst,
                                 float* __restrict__ AdjF) {
  const int e = blockIdx.x * 256 + threadIdx.x;
  if (e < E_) {
    const int s = esrc[e];
    const int d = edst[e];
    const int g = s >> 6;
    atomicAdd(AdjF + g * 4096 + (d & 63) * 64 + (s & 63), 1.0f);
  }
}

// Pre-split W (f16 hi/lo): off = (k>>3)*2048 + col*8 + (k&7); lo plane at +65536.
__global__ __launch_bounds__(256) void prep_wt(const float* __restrict__ gW1, const float* __restrict__ gW2,
                                               const float* __restrict__ Wn2n, u16* __restrict__ WTbuf) {
  const int mat = blockIdx.x;
  const float* Wsrc = (mat < 5) ? (gW1 + mat * 65536)
                    : (mat < 10) ? (gW2 + (mat - 5) * 65536) : Wn2n;
  u16* dst = WTbuf + (size_t)mat * 131072;
  const int base = blockIdx.y * 2048;
  for (int idx = base + threadIdx.x; idx < base + 2048; idx += 256) {
    const int k = idx >> 8, d = idx & 255;
    const float a = Wsrc[idx];
    u16 hi, lo; split_f16(a, hi, lo);
    const int off = (k >> 3) * 2048 + d * 8 + (k & 7);
    dst[off] = hi;
    dst[65536 + off] = lo;
  }
}

// ---------------- phase 1: encoder + iter-1 GNN + mindist, m-invariant -> once per b ----------------
__global__ __launch_bounds__(512)
void gnn1_kernel(const float* __restrict__ x, const float* __restrict__ Wenc,
                 const float* __restrict__ benc, float* __restrict__ h0g,
                 const float* __restrict__ AdjF, const u16* __restrict__ WTbuf,
                 const float* __restrict__ gb1, const float* __restrict__ gb2,
                 const float* __restrict__ eps, float* __restrict__ mindG) {
  __shared__ __align__(16) u16 hfU[256 * TROW];   // R (64x520) / T (256x136) ping-pong region
  __shared__ __align__(16) u16 AdjU[64 * 72];
  __shared__ float mindS[64];
  __shared__ float diagC[64];
  __shared__ int flagS;
  const int tid = threadIdx.x;
  const int b = blockIdx.x;

  // --- fused encoder: h0 = relu(x @ Wenc + benc) for this graph's 64 nodes ---
  // Wenc staged padded with ROW STRIDE 264 (max intra-row offset 255+7=262 < 264;
  // R8's stride 260 made rows overlap -> 3 corrupted weight columns -> argmax flip).
  {
    float* scr = (float*)hfU;                 // [0..4223) Wenc, [4300..4556) benc, [4600..5624) x
    for (int t = tid; t < 4096; t += 512) {
      const int k = t >> 8, d = t & 255;
      scr[k * 264 + d + (d >> 5)] = Wenc[t];
    }
    if (tid < 256) scr[4300 + tid] = benc[tid];
    for (int t = tid; t < 1024; t += 512) scr[4600 + t] = x[b * 1024 + t];
    __syncthreads();

    const int i = tid >> 3, part = tid & 7;
    float xv[16];
#pragma unroll
    for (int k = 0; k < 16; ++k) xv[k] = scr[4600 + i * 16 + k];
    float hv[32];
#pragma unroll
    for (int dd = 0; dd < 32; ++dd) {
      const int d = part * 32 + dd;
      float acc = scr[4300 + d];
#pragma unroll
      for (int k = 0; k < 16; ++k) acc = fmaf(xv[k], scr[k * 264 + d + (d >> 5)], acc);
      hv[dd] = fmaxf(acc, 0.f);
    }
    // write h0g (coalesced float4) for mega's build_xcur
    float* dst = h0g + (b * 64 + i) * 256 + part * 32;
#pragma unroll
    for (int dd = 0; dd < 32; dd += 4) {
      float4 v; v.x = hv[dd]; v.y = hv[dd + 1]; v.z = hv[dd + 2]; v.w = hv[dd + 3];
      *(float4*)(dst + dd) = v;
    }
    __syncthreads();                          // scratch reads done before u16 writes
    // split-write h0 into hfU (R layout) from registers
#pragma unroll
    for (int c = 0; c < 4; ++c) {
      f16x8 hi8, lo8;
#pragma unroll
      for (int e = 0; e < 8; ++e) { u16 h, l; split_f16(hv[c * 8 + e], h, l); hi8[e] = bits_h(h); lo8[e] = bits_h(l); }
      const int a = haddr8(i, part * 4 + c);
      *(f16x8*)(hfU + a) = hi8;
      *(f16x8*)(hfU + a + 8) = lo8;
    }
  }
  stage_adj(AdjU, AdjF, b, tid);
  if (tid == 0) flagS = 0;
  if (tid < 64) {
    const float dc = AdjF[b * 4096 + tid * 65];
    diagC[tid] = dc;
    int f = 0;
    for (int l = 0; l < L_; ++l) {
      const float v = dc + 1.0f + eps[l];
      if (h2f(h_bits((f16)v)) != v) f = 1;
    }
    if (f) atomicOr(&flagS, 1);
  }
  __syncthreads();
  const int slow = flagS;

  for (int l = 0; l < L_; ++l) {
    const float epsl = 1.0f + eps[l];
    if (tid < 64) AdjU[tid * 72 + tid] = h_bits((f16)(diagC[tid] + epsl));  // A' diag (pub. by G1 barriers)
    gemm_w_RT<3>(hfU, WTbuf + (size_t)l * 131072, nullptr, false);
    gemm_adj_TR<3>(hfU, AdjU, gb1 + l * D_, slow, diagC, epsl);
    gemm_w_RR<3>(hfU, WTbuf + (size_t)(5 + l) * 131072, gb2 + l * D_, true);
  }
  mindist_mfma(hfU, mindS);
  if (tid < 64) mindG[b * 64 + tid] = mindS[tid];
}

// ---------------- phase 2: per (b,m) — sample a1, iters 2..3, head ----------------
__global__ __launch_bounds__(512, 4)
void mega_kernel(const float* __restrict__ h0g, const float* __restrict__ AdjF,
                 const u16* __restrict__ WTbuf,
                 const float* __restrict__ gb1, const float* __restrict__ gb2,
                 const float* __restrict__ eps, const float* __restrict__ aemb,
                 const float* __restrict__ bn2n,
                 const float* __restrict__ Wpred, const float* __restrict__ bpred,
                 const float* __restrict__ mindG, float* __restrict__ outp) {
  __shared__ __align__(16) u16 hfU[256 * TROW];   // 69632 B R/T ping-pong (also scratch when dead)
  __shared__ __align__(16) u16 AdjU[64 * 72];     //  9216 B f16 adjacency (diag = cnt+1+eps)
  __shared__ float mindS[64];
  __shared__ float scoreS[64];
  __shared__ float hgS[256];
  __shared__ int   anchorS[64];
  __shared__ float diagC[64];
  __shared__ int   flagS;

  const int tid = threadIdx.x;
  const int b = blockIdx.x;
  const int m = blockIdx.y;

  stage_adj(AdjU, AdjF, b, tid);
  if (tid == 0) flagS = 0;
  if (tid < 64) {
    anchorS[tid] = 0;
    mindS[tid] = mindG[b * 64 + tid];
    const float dc = AdjF[b * 4096 + tid * 65];
    diagC[tid] = dc;
    int f = 0;
    for (int l = 0; l < L_; ++l) {
      const float v = dc + 1.0f + eps[l];
      if (h2f(h_bits((f16)v)) != v) f = 1;
    }
    if (f) atomicOr(&flagS, 1);
  }
  __syncthreads();

  // iter-1 sampling from precomputed mindist
  sample_anchor(mindS, scoreS, anchorS, m, b, 1, tid);
  __syncthreads();
  build_xcur<true>(hfU, h0g, aemb, anchorS, b, tid);
  __syncthreads();

  const int slow = flagS;

  // ----- iter 2: full-precision GNN (feeds argmax) -----
  for (int l = 0; l < L_; ++l) {
    const float epsl = 1.0f + eps[l];
    if (tid < 64) AdjU[tid * 72 + tid] = h_bits((f16)(diagC[tid] + epsl));
    gemm_w_RT<3>(hfU, WTbuf + (size_t)l * 131072, nullptr, false);
    gemm_adj_TR<3>(hfU, AdjU, gb1 + l * D_, slow, diagC, epsl);
    gemm_w_RR<3>(hfU, WTbuf + (size_t)(5 + l) * 131072, gb2 + l * D_, true);
  }
  mindist_mfma(hfU, mindS);
  sample_anchor(mindS, scoreS, anchorS, m, b, 2, tid);
  __syncthreads();
  build_xcur<false>(hfU, h0g, aemb, anchorS, b, tid);   // light phase: hi plane only
  __syncthreads();

  // ----- iter 3: output-path GNN, 1-term f16 hi-only (tolerance is bf16-scale) -----
  for (int l = 0; l < L_; ++l) {
    const float epsl = 1.0f + eps[l];
    if (tid < 64) AdjU[tid * 72 + tid] = h_bits((f16)(diagC[tid] + epsl));
    gemm_w_RT<1>(hfU, WTbuf + (size_t)l * 131072, nullptr, false);
    gemm_adj_TR<1>(hfU, AdjU, gb1 + l * D_, slow, diagC, epsl);
    gemm_w_RR<1>(hfU, WTbuf + (size_t)(5 + l) * 131072, gb2 + l * D_, true);
  }

  // ----- head: hn = relu(h @ W_n2n + b_n2n) (form A, R->T), mean over nodes from T rows -----
  gemm_w_RT<1>(hfU, WTbuf + (size_t)10 * 131072, bn2n, true);
  if (tid < 256) {
    float s = 0.f;
#pragma unroll
    for (int c = 0; c < 8; ++c) {
      const f16x8 v = *(const f16x8*)(hfU + taddr8(tid, c));
      s += (float)v[0] + (float)v[1] + (float)v[2] + (float)v[3]
         + (float)v[4] + (float)v[5] + (float)v[6] + (float)v[7];
    }
    hgS[tid] = s * (1.0f / 64.0f);
  }
  __syncthreads();
  if (tid < 160) {
    const int t = tid >> 4, part = tid & 15;
    float s = 0.f;
    for (int d = part * 16; d < part * 16 + 16; ++d) s = fmaf(hgS[d], Wpred[d * TASKS_ + t], s);
    s += __shfl_xor(s, 1); s += __shfl_xor(s, 2); s += __shfl_xor(s, 4); s += __shfl_xor(s, 8);
    if (part == 0) {
      float val = s * 0.25f;
      if (m == 0) val += bpred[t];
      atomicAdd(outp + b * TASKS_ + t, val);
    }
  }
}

// ---------------- launch ----------------
extern "C" void kernel_launch(void* const* d_in, const int* in_sizes, int n_in,
                              void* d_out, int out_size, void* d_ws, size_t ws_size,
                              hipStream_t stream) {
  const float* x     = (const float*)d_in[0];
  const float* Wenc  = (const float*)d_in[1];
  const float* benc  = (const float*)d_in[2];
  const float* gW1   = (const float*)d_in[3];
  const float* gb1   = (const float*)d_in[4];
  const float* gW2   = (const float*)d_in[5];
  const float* gb2   = (const float*)d_in[6];
  const float* eps   = (const float*)d_in[7];
  const float* aemb  = (const float*)d_in[8];
  const float* Wn2n  = (const float*)d_in[9];
  const float* bn2n  = (const float*)d_in[10];
  const float* Wpred = (const float*)d_in[11];
  const float* bpred = (const float*)d_in[12];
  const int* esrc    = (const int*)d_in[13];
  const int* edst    = (const int*)d_in[14];
  float* outp = (float*)d_out;

  float* h0g  = (float*)d_ws;                      // 16 MB
  float* AdjF = h0g + (size_t)N_ * D_;             // 4 MB
  u16* WTbuf  = (u16*)(AdjF + B_ * 4096);          // 11 * 256 KB f16 split weights
  float* mindG = (float*)(WTbuf + (size_t)11 * 131072);   // B*64 floats

  hipMemsetAsync(AdjF, 0, (size_t)B_ * 4096 * sizeof(float), stream);
  hipMemsetAsync(outp, 0, (size_t)out_size * sizeof(float), stream);
  build_adj_kernel<<<dim3((E_ + 255) / 256), dim3(256), 0, stream>>>(esrc, edst, AdjF);
  prep_wt<<<dim3(11, 32), dim3(256), 0, stream>>>(gW1, gW2, Wn2n, WTbuf);
  gnn1_kernel<<<dim3(B_), dim3(512), 0, stream>>>(x, Wenc, benc, h0g, AdjF, WTbuf,
                                                  gb1, gb2, eps, mindG);
  mega_kernel<<<dim3(B_, M_), dim3(512), 0, stream>>>(h0g, AdjF, WTbuf, gb1, gb2,
                                                      eps, aemb, bn2n, Wpred, bpred, mindG, outp);
}